// Round 1
// 183.313 us; speedup vs baseline: 1.0555x; 1.0555x over previous
//
#include <hip/hip_runtime.h>

#define DIM   1024
#define HEADS 16
#define HDIM  64
#define BATCH 2
#define SEQ   2048
#define TOK   (BATCH*SEQ)   // 4096
#define MEG   1048576

typedef __bf16 bf16x8 __attribute__((ext_vector_type(8)));
typedef float  f32x4  __attribute__((ext_vector_type(4)));
typedef float  f32x16 __attribute__((ext_vector_type(16)));

__device__ __forceinline__ float b2f(ushort u) {
    union { unsigned int u32; float f; } x; x.u32 = ((unsigned int)u) << 16; return x.f;
}
__device__ __forceinline__ ushort f2b(float f) {
    union { float f; unsigned int u32; } x; x.f = f;
    unsigned int r = x.u32 + 0x7FFFu + ((x.u32 >> 16) & 1u);
    return (ushort)(r >> 16);
}
// async global->LDS, 16B per lane; lds dest = wave-uniform base + lane*16
__device__ __forceinline__ void gload_lds16(const ushort* g, void* l) {
    __builtin_amdgcn_global_load_lds((const __attribute__((address_space(1))) void*)g,
                                     (__attribute__((address_space(3))) void*)l, 16, 0, 0);
}
__device__ __forceinline__ float fexp2(float x) {   // 2^x, single v_exp_f32
    float r; asm("v_exp_f32 %0, %1" : "=v"(r) : "v"(x)); return r;
}
__device__ __forceinline__ unsigned int cvtpk_bf16(float lo, float hi) {
    unsigned int r; asm("v_cvt_pk_bf16_f32 %0, %1, %2" : "=v"(r) : "v"(lo), "v"(hi)); return r;
}
// swap a's upper 32 lanes with b's lower 32 lanes:
// after: a = {a[0:31], b[0:31]}, b = {a[32:63], b[32:63]}
__device__ __forceinline__ void plane32swap(unsigned int &a, unsigned int &b) {
    asm("v_permlane32_swap_b32 %0, %1" : "+v"(a), "+v"(b));
}

// ------- tiled transpose + fp32->bf16 cast: src f32[R][Cc] -> dst bf16[Cc][R]
__global__ void transpose_f2b_k(const float* __restrict__ src, ushort* __restrict__ dst,
                                int R, int Cc) {
    __shared__ ushort tile[32][33];
    int c0 = blockIdx.x * 32, r0 = blockIdx.y * 32;
    int tx = threadIdx.x, ty = threadIdx.y;   // 32 x 8
#pragma unroll
    for (int i = 0; i < 4; i++)
        tile[ty + 8 * i][tx] = f2b(src[(long)(r0 + ty + 8 * i) * Cc + c0 + tx]);
    __syncthreads();
#pragma unroll
    for (int i = 0; i < 4; i++)
        dst[(long)(c0 + ty + 8 * i) * R + r0 + tx] = tile[tx][ty + 8 * i];
}

// ------- LayerNorm: one block per token, fp32 in -> bf16 out -----------------
__global__ __launch_bounds__(256)
void ln_k(const float* __restrict__ x, const float* __restrict__ gamma,
          const float* __restrict__ beta, ushort* __restrict__ h) {
    __shared__ float red[8];
    int row = blockIdx.x, tid = threadIdx.x;
    const float* xr = x + (long)row * DIM;
    float4 xv = *(const float4*)(xr + tid * 4);
    float s1 = xv.x + xv.y + xv.z + xv.w;
    float s2 = xv.x * xv.x + xv.y * xv.y + xv.z * xv.z + xv.w * xv.w;
#pragma unroll
    for (int off = 32; off; off >>= 1) {
        s1 += __shfl_down(s1, off);
        s2 += __shfl_down(s2, off);
    }
    int wid = tid >> 6, lane = tid & 63;
    if (lane == 0) { red[wid * 2] = s1; red[wid * 2 + 1] = s2; }
    __syncthreads();
    s1 = red[0] + red[2] + red[4] + red[6];
    s2 = red[1] + red[3] + red[5] + red[7];
    float mu  = s1 * (1.0f / DIM);
    float var = s2 * (1.0f / DIM) - mu * mu;
    float rs  = rsqrtf(var + 1e-5f);
    float4 gv = *(const float4*)(gamma + tid * 4);
    float4 bv = *(const float4*)(beta + tid * 4);
    ushort4 ov;
    ov.x = f2b((xv.x - mu) * rs * gv.x + bv.x);
    ov.y = f2b((xv.y - mu) * rs * gv.y + bv.y);
    ov.z = f2b((xv.z - mu) * rs * gv.z + bv.z);
    ov.w = f2b((xv.w - mu) * rs * gv.w + bv.w);
    *(ushort4*)(h + (long)row * DIM + tid * 4) = ov;
}

// ------- QKV GEMM: 128x128 tile, BK=64, global_load_lds staging --------------
// Col-tiles < 2048: scatter q/k to [B,H,N,D] (q pre-scaled 1/8 * log2e so the
// attention softmax can use bare v_exp_f32 = 2^x).
// Col-tiles >= 2048 (pure V): LDS-transpose acc and write V^T [B,H][D][N].
__global__ __launch_bounds__(256, 3)
void gemm_qkv_k(const ushort* __restrict__ A, const ushort* __restrict__ Bt,
                ushort* __restrict__ qp, ushort* __restrict__ kp, ushort* __restrict__ vp) {
    __shared__ ushort smem[16384];   // As: [0,8192) Bs: [8192,16384); reused as T[128][128]
    int tid  = threadIdx.x;
    int wid  = tid >> 6, lane = tid & 63;
    int quad = lane >> 4, l16 = lane & 15;
    int wm = wid >> 1, wn = wid & 1;
    int rowbase = blockIdx.y * 128;
    int colbase = blockIdx.x * 128;

    f32x4 acc[4][4];
#pragma unroll
    for (int i = 0; i < 4; i++)
#pragma unroll
        for (int j = 0; j < 4; j++) acc[i][j] = (f32x4){0.f, 0.f, 0.f, 0.f};

    for (int k0 = 0; k0 < DIM; k0 += 64) {
#pragma unroll
        for (int p = 0; p < 2; p++) {
            int c = wid * 2 + p;
            int r = c * 16 + (lane >> 2);
            int ac = (lane & 3) * 8;
#pragma unroll
            for (int pnl = 0; pnl < 2; pnl++) {
                int cc = k0 + pnl * 32 + ac;
                gload_lds16(A  + (long)(rowbase + r) * DIM + cc,
                            &smem[pnl * 4096 + c * 16 * 32]);
                gload_lds16(Bt + (long)(colbase + r) * DIM + cc,
                            &smem[8192 + pnl * 4096 + c * 16 * 32]);
            }
        }
        __syncthreads();
#pragma unroll
        for (int pnl = 0; pnl < 2; pnl++) {
            bf16x8 fa[4], fb[4];
#pragma unroll
            for (int t = 0; t < 4; t++)
                fa[t] = *(const bf16x8*)(&smem[pnl * 4096 + (wm * 64 + t * 16 + l16) * 32 + quad * 8]);
#pragma unroll
            for (int t = 0; t < 4; t++)
                fb[t] = *(const bf16x8*)(&smem[8192 + pnl * 4096 + (wn * 64 + t * 16 + l16) * 32 + quad * 8]);
#pragma unroll
            for (int i = 0; i < 4; i++)
#pragma unroll
                for (int j = 0; j < 4; j++)
                    acc[i][j] = __builtin_amdgcn_mfma_f32_16x16x32_bf16(fa[i], fb[j], acc[i][j], 0, 0, 0);
        }
        __syncthreads();
    }

    if (colbase >= 2048) {
        // V block: acc -> T[col_local][row_local] -> coalesced V^T write
#pragma unroll
        for (int i = 0; i < 4; i++)
#pragma unroll
            for (int j = 0; j < 4; j++) {
                int cl = wn * 64 + j * 16 + l16;
                int rl = wm * 64 + i * 16 + quad * 4;
#pragma unroll
                for (int r = 0; r < 4; r++)
                    smem[cl * 128 + rl + r] = f2b(acc[i][j][r]);
            }
        __syncthreads();
        int b = rowbase >> 11, nnb = rowbase & 2047;
        int hbase = (colbase - 2048) >> 6;
#pragma unroll
        for (int i = 0; i < 8; i++) {
            int id = i * 256 + tid;           // 0..2047
            int cl = id >> 4;                 // local col 0..127
            int off = (id & 15) * 8;          // 0..120
            int hh = hbase + (cl >> 6), d = cl & 63;
            uint4 val = *(const uint4*)(&smem[cl * 128 + off]);
            *(uint4*)(vp + (((long)b * HEADS + hh) * HDIM + d) * SEQ + nnb + off) = val;
        }
    } else {
#pragma unroll
        for (int i = 0; i < 4; i++)
#pragma unroll
            for (int j = 0; j < 4; j++) {
                int m0  = rowbase + wm * 64 + i * 16 + quad * 4;
                int col = colbase + wn * 64 + j * 16 + l16;
                int part = col >> 10, rem = col & 1023;
                int head = rem >> 6, d = rem & 63;
                ushort* dst = (part == 0) ? qp : kp;
#pragma unroll
                for (int r = 0; r < 4; r++) {
                    float v = acc[i][j][r];
                    int mm = m0 + r;
                    int b = mm >> 11, nn = mm & 2047;
                    // q scale = 1/sqrt(64) * log2(e)  (softmax uses 2^x)
                    float sv = (part == 0) ? v * 0.18033688011f : v;
                    dst[((((long)b * HEADS + head) * SEQ + nn) << 6) + d] = f2b(sv);
                }
            }
    }
}

// ------- Proj GEMM: 128x64 tile, BK=64; grid 512 -----------------------------
__global__ __launch_bounds__(256, 3)
void gemm_proj_k(const ushort* __restrict__ A, const ushort* __restrict__ Bt,
                 const float* __restrict__ bias, const float* __restrict__ xres,
                 float* __restrict__ outp) {
    __shared__ ushort As[2][128][32];   // 16 KB
    __shared__ ushort Bs[2][64][32];    // 8 KB
    int tid  = threadIdx.x;
    int wid  = tid >> 6, lane = tid & 63;
    int quad = lane >> 4, l16 = lane & 15;
    int rowbase = blockIdx.y * 128;
    int colbase = blockIdx.x * 64;
    int arow = lane >> 2, acol = (lane & 3) * 8;

    f32x4 acc[2][4];
#pragma unroll
    for (int i = 0; i < 2; i++)
#pragma unroll
        for (int j = 0; j < 4; j++) acc[i][j] = (f32x4){0.f, 0.f, 0.f, 0.f};

    for (int k0 = 0; k0 < DIM; k0 += 64) {
#pragma unroll
        for (int p = 0; p < 2; p++) {
            int c = wid * 2 + p;
            int r = c * 16 + arow;
            int mm = rowbase + r;
            int bq = mm >> 11, nn = mm & 2047;
#pragma unroll
            for (int pnl = 0; pnl < 2; pnl++) {
                int cc = k0 + pnl * 32 + acol;
                int head = cc >> 6, d = cc & 63;
                gload_lds16(A + ((((long)bq * HEADS + head) * SEQ + nn) << 6) + d,
                            &As[pnl][c * 16][0]);
            }
        }
        {
            int r = wid * 16 + arow;
#pragma unroll
            for (int pnl = 0; pnl < 2; pnl++) {
                int cc = k0 + pnl * 32 + acol;
                gload_lds16(Bt + (long)(colbase + r) * DIM + cc, &Bs[pnl][wid * 16][0]);
            }
        }
        __syncthreads();
#pragma unroll
        for (int pnl = 0; pnl < 2; pnl++) {
            bf16x8 fa[2], fb[4];
#pragma unroll
            for (int t = 0; t < 2; t++)
                fa[t] = *(const bf16x8*)(&As[pnl][wid * 32 + t * 16 + l16][quad * 8]);
#pragma unroll
            for (int t = 0; t < 4; t++)
                fb[t] = *(const bf16x8*)(&Bs[pnl][t * 16 + l16][quad * 8]);
#pragma unroll
            for (int i = 0; i < 2; i++)
#pragma unroll
                for (int j = 0; j < 4; j++)
                    acc[i][j] = __builtin_amdgcn_mfma_f32_16x16x32_bf16(fa[i], fb[j], acc[i][j], 0, 0, 0);
        }
        __syncthreads();
    }

#pragma unroll
    for (int i = 0; i < 2; i++)
#pragma unroll
        for (int j = 0; j < 4; j++) {
            int m0  = rowbase + wid * 32 + i * 16 + quad * 4;
            int col = colbase + j * 16 + l16;
#pragma unroll
            for (int r = 0; r < 4; r++) {
                int mm = m0 + r;
                outp[(long)mm * DIM + col] = acc[i][j][r] + bias[col] + xres[(long)mm * DIM + col];
            }
        }
}

// ------- flash attention, 32x32 MFMA, fully in-register softmax --------------
// Swapped QK^T: C[key][q] with col=q=lane&31, row=key=(reg&3)+8*(reg>>2)+4*hi.
// P -> bf16 A-frags via v_cvt_pk_bf16_f32 + v_permlane32_swap_b32 (no P LDS
// round-trip, no lgkmcnt join between QK^T and PV).
// LDS layouts use 16B-slot XOR swizzles so every ds_read/ds_write_b128 has a
// uniform 8-lanes-per-4-bank-group distribution (bank-conflict floor):
//   K:  [32 key][64 d], slot(c16) stored at c16 ^ (row&7)     (8 slots/row)
//   V:  [64 d][32 k],   slot(c4)  stored at c4  ^ (d&3)       (4 slots/row)
__global__ __launch_bounds__(256, 4)
void attn_k(ushort* qio, const ushort* __restrict__ kg,
            const ushort* __restrict__ vt) {
    __shared__ __align__(16) ushort Kp[2][2048];   // 8 KB: [buf] 32x64 swizzled
    __shared__ __align__(16) ushort Vs[2][2048];   // 8 KB: [buf] 64x32 swizzled
    int bh = blockIdx.y;
    int tid = threadIdx.x, wid = tid >> 6, lane = tid & 63;
    int l31 = lane & 31, hi = lane >> 5;
    ushort* qh = qio + (long)bh * SEQ * HDIM;
    const ushort* kh = kg + (long)bh * SEQ * HDIM;
    const ushort* vh = vt + (long)bh * HDIM * SEQ;

    // staging: K tile 32x64 (1 uint4/thread), V^T tile 64x32 (1 uint4/thread)
    int kr = tid & 31, kc = tid >> 5;                 // K row, 8-ushort chunk 0..7
    int kofs = kr * 64 + ((kc ^ (kr & 7)) * 8);       // swizzled LDS dest
    int vrow = tid & 63;
    int vslot = ((tid >> 6) + (vrow >> 1)) & 3;       // uniform write slots
    int vgc = (vslot ^ (vrow & 3)) * 8;               // global chunk col (ushorts)
    int vofs = vrow * 32 + vslot * 8;

    int qrow0 = blockIdx.x * 128 + wid * 32;
    // Q B-frag: lane holds Q[q=l31][d = ks*16 + hi*8 + j] -- direct row load
    bf16x8 qf[4];
#pragma unroll
    for (int ks = 0; ks < 4; ks++)
        qf[ks] = *(const bf16x8*)(qh + (long)(qrow0 + l31) * HDIM + ks * 16 + hi * 8);

    f32x16 o0 = {}, o1 = {};                // PV acc: col=d=l31(+32), row=q map
    f32x4 lac = {0.f, 0.f, 0.f, 0.f};       // per-column (q) exp sums

    uint4 kreg = *(const uint4*)(kh + (long)kr * HDIM + kc * 8);
    uint4 vreg = *(const uint4*)(vh + (long)vrow * SEQ + vgc);
    *(uint4*)(&Kp[0][kofs]) = kreg;
    *(uint4*)(&Vs[0][vofs]) = vreg;

    const int NIT = SEQ / 32;   // 64
    for (int it = 0; it < NIT; ++it) {
        int buf = it & 1;
        if (it + 1 < NIT) {
            int kt = (it + 1) * 32;
            kreg = *(const uint4*)(kh + (long)(kt + kr) * HDIM + kc * 8);
            vreg = *(const uint4*)(vh + (long)vrow * SEQ + kt + vgc);
        }
        __syncthreads();

        // QK^T: A = K[key][d], B = Q^T[d][q]
        f32x16 sc = {};
        __builtin_amdgcn_s_setprio(1);
#pragma unroll
        for (int ks = 0; ks < 4; ks++) {
            bf16x8 kb = *(const bf16x8*)(
                &Kp[buf][l31 * 64 + (((2 * ks + hi) ^ (l31 & 7)) * 8)]);
            sc = __builtin_amdgcn_mfma_f32_32x32x16_bf16(kb, qf[ks], sc, 0, 0, 0);
        }
        __builtin_amdgcn_s_setprio(0);

        // softmax numerators: 2^(sc) (log2e folded into q scale)
        float e[16];
#pragma unroll
        for (int r = 0; r < 16; r++) e[r] = fexp2(sc[r]);
#pragma unroll
        for (int r = 0; r < 4; r++)
            lac += (f32x4){e[4 * r], e[4 * r + 1], e[4 * r + 2], e[4 * r + 3]};

        // P -> A-frags. regs r hold keys (r&3)+8*(r>>2)+4*hi; cvt_pk pairs are
        // consecutive keys; permlane32_swap exchanges hi/lo half key-groups.
        unsigned int pk0 = cvtpk_bf16(e[0], e[1]),   pk1 = cvtpk_bf16(e[2], e[3]);
        unsigned int pk2 = cvtpk_bf16(e[4], e[5]),   pk3 = cvtpk_bf16(e[6], e[7]);
        unsigned int pk4 = cvtpk_bf16(e[8], e[9]),   pk5 = cvtpk_bf16(e[10], e[11]);
        unsigned int pk6 = cvtpk_bf16(e[12], e[13]), pk7 = cvtpk_bf16(e[14], e[15]);
        plane32swap(pk0, pk2);   // pa0.d0 / pa0.d2  (keys 0..7 | 8..15)
        plane32swap(pk1, pk3);   // pa0.d1 / pa0.d3
        plane32swap(pk4, pk6);   // pa1.d0 / pa1.d2  (keys 16..23 | 24..31)
        plane32swap(pk5, pk7);   // pa1.d1 / pa1.d3
        union { unsigned int u[4]; bf16x8 v; } pa0, pa1;
        pa0.u[0] = pk0; pa0.u[1] = pk1; pa0.u[2] = pk2; pa0.u[3] = pk3;
        pa1.u[0] = pk4; pa1.u[1] = pk5; pa1.u[2] = pk6; pa1.u[3] = pk7;

        // PV: A = P[q][k], B = V[k][d] from Vs[d][k] column slices
        __builtin_amdgcn_s_setprio(1);
        {
            int d0 = l31;
            bf16x8 v00 = *(const bf16x8*)(&Vs[buf][d0 * 32 + ((hi ^ (d0 & 3)) * 8)]);
            bf16x8 v01 = *(const bf16x8*)(&Vs[buf][d0 * 32 + (((2 + hi) ^ (d0 & 3)) * 8)]);
            o0 = __builtin_amdgcn_mfma_f32_32x32x16_bf16(pa0.v, v00, o0, 0, 0, 0);
            o0 = __builtin_amdgcn_mfma_f32_32x32x16_bf16(pa1.v, v01, o0, 0, 0, 0);
            int d1 = 32 + l31;
            bf16x8 v10 = *(const bf16x8*)(&Vs[buf][d1 * 32 + ((hi ^ (d1 & 3)) * 8)]);
            bf16x8 v11 = *(const bf16x8*)(&Vs[buf][d1 * 32 + (((2 + hi) ^ (d1 & 3)) * 8)]);
            o1 = __builtin_amdgcn_mfma_f32_32x32x16_bf16(pa0.v, v10, o1, 0, 0, 0);
            o1 = __builtin_amdgcn_mfma_f32_32x32x16_bf16(pa1.v, v11, o1, 0, 0, 0);
        }
        __builtin_amdgcn_s_setprio(0);

        if (it + 1 < NIT) {
            *(uint4*)(&Kp[buf ^ 1][kofs]) = kreg;
            *(uint4*)(&Vs[buf ^ 1][vofs]) = vreg;
        }
    }

    // denominators: column q sums split across lane pair (q, q+32)
    float t = lac[0] + lac[1] + lac[2] + lac[3];
    t += __shfl_xor(t, 32);
    float linv = 1.0f / t;          // valid in lanes q and q+32 for column q=l31
#pragma unroll
    for (int r = 0; r < 16; r++) {
        int qrow = (r & 3) + 8 * (r >> 2) + 4 * hi;
        float lr = __shfl(linv, qrow);        // lane qrow holds 1/sum for q=qrow
        long ro = (long)(qrow0 + qrow) * HDIM;
        qh[ro + l31]      = f2b(o0[r] * lr);
        qh[ro + 32 + l31] = f2b(o1[r] * lr);
    }
}

// ------- launch --------------------------------------------------------------
extern "C" void kernel_launch(void* const* d_in, const int* in_sizes, int n_in,
                              void* d_out, int out_size, void* d_ws, size_t ws_size,
                              hipStream_t stream) {
    const float* x      = (const float*)d_in[0];
    const float* w_qkv  = (const float*)d_in[1];
    const float* w_proj = (const float*)d_in[2];
    const float* b_proj = (const float*)d_in[3];
    const float* gamma  = (const float*)d_in[4];
    const float* beta   = (const float*)d_in[5];
    float* out = (float*)d_out;

    // workspace: 19M bf16 elements = 38 MB
    ushort* ws   = (ushort*)d_ws;
    ushort* h    = ws;                      // 4M: LN output
    ushort* wqt  = ws + (size_t)4 * MEG;    // 3M: w_qkv^T (bf16)
    ushort* qb   = ws + (size_t)7 * MEG;    // 4M: q (pre-scaled), then attn out (q-layout)
    ushort* kb   = ws + (size_t)11 * MEG;   // 4M: k, then w_proj^T
    ushort* vtb  = ws + (size_t)15 * MEG;   // 4M: V^T [B,H][D][N] (written by QKV epilogue)

    // 1) transpose+cast w_qkv f32[K][3N] -> bf16 [3N][K]
    transpose_f2b_k<<<dim3(3 * DIM / 32, DIM / 32), dim3(32, 8), 0, stream>>>(
        w_qkv, wqt, DIM, 3 * DIM);
    // 2) layernorm f32 -> bf16 h
    ln_k<<<dim3(TOK), dim3(256), 0, stream>>>(x, gamma, beta, h);
    // 3) qkv gemm: scatter q/k, V^T written directly (fused transpose)
    gemm_qkv_k<<<dim3(3 * DIM / 128, TOK / 128), dim3(256), 0, stream>>>(
        h, wqt, qb, kb, vtb);
    // 4) flash attention; output overwrites q buffer in q-layout
    attn_k<<<dim3(SEQ / 128, BATCH * HEADS), dim3(256), 0, stream>>>(qb, kb, vtb);
    // 5) transpose+cast w_proj into dead k slot
    transpose_f2b_k<<<dim3(DIM / 32, DIM / 32), dim3(32, 8), 0, stream>>>(
        w_proj, kb, DIM, DIM);
    // 6) proj gemm (+fp32 bias +fp32 residual) -> fp32 out, 128x64 tiles
    gemm_proj_k<<<dim3(DIM / 64, TOK / 128), dim3(256), 0, stream>>>(
        qb, kb, b_proj, x, out);
}